// Round 1
// baseline (410.952 us; speedup 1.0000x reference)
//
#include <hip/hip_runtime.h>

#define BLANKC 2
#define NEGV (-1e30f)

__device__ __forceinline__ float lae3(float a, float b, float c) {
    float m = fmaxf(fmaxf(a, b), c);
    return m + __logf(__expf(a - m) + __expf(b - m) + __expf(c - m));
}

__device__ __forceinline__ float sel3(int e, float v0, float v1, float v2) {
    return (e == 2) ? v2 : ((e == 1) ? v1 : v0);
}

// One wave (64 lanes) per (b,f) pair. Each lane owns 3 adjacent lattice
// states in registers; neighbors come via shfl_up. L = 2S+1 must be <= 192.
__global__ __launch_bounds__(64) void ctc_kernel(
    const float* __restrict__ logits,        // [T, B, 2F+1]
    const int* __restrict__ targets,         // [B, F, S]
    const int* __restrict__ input_lengths,   // [B]
    const int* __restrict__ target_lengths,  // [B, F]
    float* __restrict__ loss_out,            // [B*F]  (already divided by tl)
    int T, int B, int Ff, int S)
{
    const int p = blockIdx.x;
    const int b = p / Ff;
    const int f = p - b * Ff;
    const int lane = (int)threadIdx.x;
    const int C = 2 * Ff + 1;
    const int L = 2 * S + 1;

    const int tl = target_lengths[p];
    const int il = input_lengths[b];
    const int Lv = 2 * tl + 1;
    const int tbase = p * S;

    // ---- per-lane static lattice metadata (3 states: l = 3*lane + j) ----
    int  e0i = BLANKC, e1i = BLANKC, e2i = BLANKC;
    bool sk0 = false, sk1 = false, sk2 = false;
    bool vv0 = false, vv1 = false, vv2 = false;
    {
        const int l0 = 3 * lane;
        // j = 0
        {
            int l = l0; bool inL = (l < L); int ev = BLANKC; bool sok = false;
            if (inL && (l & 1)) {
                int s = (l - 1) >> 1;
                ev = targets[tbase + s];
                if (s >= 1) sok = (targets[tbase + s - 1] != ev);
            }
            e0i = ev; sk0 = sok; vv0 = inL && (l < Lv);
        }
        // j = 1
        {
            int l = l0 + 1; bool inL = (l < L); int ev = BLANKC; bool sok = false;
            if (inL && (l & 1)) {
                int s = (l - 1) >> 1;
                ev = targets[tbase + s];
                if (s >= 1) sok = (targets[tbase + s - 1] != ev);
            }
            e1i = ev; sk1 = sok; vv1 = inL && (l < Lv);
        }
        // j = 2
        {
            int l = l0 + 2; bool inL = (l < L); int ev = BLANKC; bool sok = false;
            if (inL && (l & 1)) {
                int s = (l - 1) >> 1;
                ev = targets[tbase + s];
                if (s >= 1) sok = (targets[tbase + s - 1] != ev);
            }
            e2i = ev; sk2 = sok; vv2 = inL && (l < Lv);
        }
    }

    const float* base = logits + (size_t)b * C;
    const size_t strideT = (size_t)B * C;

    // ---- t = 0 init ----
    float a0, a1, a2;
    {
        float xp = base[f], xn = base[Ff + f], xb = base[2 * Ff];
        float m = fmaxf(fmaxf(xp, xn), xb);
        float ls = m + __logf(__expf(xp - m) + __expf(xn - m) + __expf(xb - m));
        float lp0 = xp - ls, lp1 = xn - ls, lp2 = xb - ls;
        a0 = (lane == 0) ? lp2 : NEGV;                                   // ext[0] = blank
        a1 = (lane == 0 && tl > 0) ? sel3(e1i, lp0, lp1, lp2) : NEGV;    // ext[1] = targets[0]
        a2 = NEGV;
    }

    // ---- main recursion over t (prefetch next row's 3 logits) ----
    const int t_end = (il < T) ? il : T;
    float yp = 0.f, yn = 0.f, ybv = 0.f;
    if (t_end > 1) {
        const float* r = base + strideT;   // t = 1
        yp = r[f]; yn = r[Ff + f]; ybv = r[2 * Ff];
    }
    for (int t = 1; t < t_end; ++t) {
        const float cp = yp, cn = yn, cb = ybv;
        // prefetch t+1 (clamped; redundant on final iter)
        {
            int tn = (t + 1 < t_end) ? (t + 1) : t;
            const float* r = base + (size_t)tn * strideT;
            yp = r[f]; yn = r[Ff + f]; ybv = r[2 * Ff];
        }

        float m = fmaxf(fmaxf(cp, cn), cb);
        float ls = m + __logf(__expf(cp - m) + __expf(cn - m) + __expf(cb - m));
        float lp0 = cp - ls, lp1 = cn - ls, lp2 = cb - ls;

        float am1 = __shfl_up(a2, 1);   // alpha[3*lane - 1]
        float am2 = __shfl_up(a1, 1);   // alpha[3*lane - 2]
        if (lane == 0) { am1 = NEGV; am2 = NEGV; }

        float em0 = sel3(e0i, lp0, lp1, lp2);
        float em1 = sel3(e1i, lp0, lp1, lp2);
        float em2 = sel3(e2i, lp0, lp1, lp2);

        float n0 = vv0 ? (lae3(a0, am1, sk0 ? am2 : NEGV) + em0) : NEGV;
        float n1 = vv1 ? (lae3(a1, a0,  sk1 ? am1 : NEGV) + em1) : NEGV;
        float n2 = vv2 ? (lae3(a2, a1,  sk2 ? a0  : NEGV) + em2) : NEGV;
        a0 = n0; a1 = n1; a2 = n2;
    }

    // ---- epilogue: gather alpha[2*tl], alpha[2*tl-1] ----
    __shared__ float sa[192];
    {
        int l = 3 * lane;
        if (l < L)     sa[l]     = a0;
        if (l + 1 < L) sa[l + 1] = a1;
        if (l + 2 < L) sa[l + 2] = a2;
    }
    __syncthreads();
    if (lane == 0) {
        float last = sa[2 * tl];
        float prv  = (tl > 0) ? sa[2 * tl - 1] : NEGV;
        float m  = fmaxf(last, prv);
        float ll = m + __logf(__expf(last - m) + __expf(prv - m));
        float loss = (ll > -1e29f) ? -ll : 0.0f;
        float denom = (tl > 0) ? (float)tl : 1.0f;
        loss_out[p] = loss / denom;
    }
}

// Deterministic single-block reduction: out[0] = sum(v) / B
__global__ __launch_bounds__(256) void reduce_kernel(
    const float* __restrict__ v, float* __restrict__ out, int n, float invB)
{
    __shared__ float buf[256];
    float s = 0.f;
    for (int i = (int)threadIdx.x; i < n; i += 256) s += v[i];
    buf[threadIdx.x] = s;
    __syncthreads();
    for (int off = 128; off > 0; off >>= 1) {
        if ((int)threadIdx.x < off) buf[threadIdx.x] += buf[threadIdx.x + off];
        __syncthreads();
    }
    if (threadIdx.x == 0) out[0] = buf[0] * invB;
}

extern "C" void kernel_launch(void* const* d_in, const int* in_sizes, int n_in,
                              void* d_out, int out_size, void* d_ws, size_t ws_size,
                              hipStream_t stream) {
    const float* logits         = (const float*)d_in[0];
    const int*   targets        = (const int*)d_in[1];
    const int*   input_lengths  = (const int*)d_in[2];
    const int*   target_lengths = (const int*)d_in[3];
    float* out = (float*)d_out;

    const int B  = in_sizes[2];            // 32
    const int BF = in_sizes[3];            // B*F = 1120
    const int Ff = BF / B;                 // 35
    const int S  = in_sizes[1] / BF;       // 80
    const int C  = 2 * Ff + 1;             // 71
    const int T  = in_sizes[0] / (B * C);  // 600

    float* losses = (float*)d_ws;          // BF floats of scratch

    ctc_kernel<<<BF, 64, 0, stream>>>(logits, targets, input_lengths,
                                      target_lengths, losses, T, B, Ff, S);
    reduce_kernel<<<1, 256, 0, stream>>>(losses, out, BF, 1.0f / (float)B);
}

// Round 3
// 241.877 us; speedup vs baseline: 1.6990x; 1.6990x over previous
//
#include <hip/hip_runtime.h>

#define BLANKC 2
#define NEGV (-1e30f)

// lane i <- lane i-1; lane 0 <- NEGV. v_mov_b32_dpp wave_shr:1 (~4cy vs ~50cy ds_bpermute).
__device__ __forceinline__ float dpp_shr1_neg(float x) {
    return __int_as_float(__builtin_amdgcn_update_dpp(
        __float_as_int(NEGV), __float_as_int(x), 0x138, 0xF, 0xF, false));
}

__device__ __forceinline__ float lae3(float a, float b, float c) {
    float m = fmaxf(fmaxf(a, b), c);          // v_max3_f32
    return m + __logf(__expf(a - m) + __expf(b - m) + __expf(c - m));
}

__device__ __forceinline__ float sel3(int e, float v0, float v1, float v2) {
    return (e == 2) ? v2 : ((e == 1) ? v1 : v0);
}

// One wave per (b,f). Lane owns 3 adjacent lattice states in registers (log domain,
// exact R1 semantics); log-softmax emissions staged once in LDS; neighbors via DPP.
__global__ __launch_bounds__(64) void ctc_kernel(
    const float* __restrict__ logits,        // [T, B, 2F+1]
    const int* __restrict__ targets,         // [B, F, S]
    const int* __restrict__ input_lengths,   // [B]
    const int* __restrict__ target_lengths,  // [B, F]
    float* __restrict__ loss_out,            // [B*F] (loss / tl)
    int T, int B, int Ff, int S)
{
    const int p = blockIdx.x;
    const int b = p / Ff;
    const int f = p - b * Ff;
    const int lane = (int)threadIdx.x;
    const int C = 2 * Ff + 1;
    const int L = 2 * S + 1;

    const int tl = target_lengths[p];
    const int il = input_lengths[b];
    const int Lv = 2 * tl + 1;
    const int tbase = p * S;

    // ---- per-lane static metadata: states l = 3*lane + j ----
    int  e0i, e1i, e2i;
    bool sk0, sk1, sk2, vv0, vv1, vv2;
    {
        int e[3]; bool sk[3], vv[3];
        const int l0 = 3 * lane;
        #pragma unroll
        for (int j = 0; j < 3; ++j) {
            int l = l0 + j;
            int ev = BLANKC; bool sok = false;
            bool inL = (l < L);
            if (inL && (l & 1)) {
                int s = (l - 1) >> 1;
                ev = targets[tbase + s];
                if (s >= 1) sok = (targets[tbase + s - 1] != ev);
            }
            e[j] = ev; sk[j] = sok; vv[j] = inL && (l < Lv);
        }
        e0i = e[0]; e1i = e[1]; e2i = e[2];
        sk0 = sk[0]; sk1 = sk[1]; sk2 = sk[2];
        vv0 = vv[0]; vv1 = vv[1]; vv2 = vv[2];
    }

    // ---- stage log-softmax into LDS: slp[t] = {lp_pos, lp_neg, lp_blank, 0} ----
    __shared__ float4 slp[602];   // T+2, tail zero-padded for prefetch overrun
    {
        const float* lg = logits + (size_t)b * C;
        const size_t strideT = (size_t)B * C;
        for (int i = lane; i < T + 2; i += 64) {
            float4 v = make_float4(0.f, 0.f, 0.f, 0.f);
            if (i < T) {
                const float* r = lg + (size_t)i * strideT;
                float xp = r[f], xn = r[Ff + f], xb = r[2 * Ff];
                float m = fmaxf(fmaxf(xp, xn), xb);
                float ls = m + __logf(__expf(xp - m) + __expf(xn - m) + __expf(xb - m));
                v = make_float4(xp - ls, xn - ls, xb - ls, 0.f);
            }
            slp[i] = v;
        }
    }
    __syncthreads();

    // ---- t = 0 init ----
    float4 E0 = slp[0];
    float a0 = (lane == 0) ? E0.z : NEGV;
    float a1 = (lane == 0 && tl > 0) ? sel3(e1i, E0.x, E0.y, E0.z) : NEGV;
    float a2 = NEGV;

    // ---- main recursion (log domain), 2-deep LDS prefetch ----
    const int t_end = (il < T) ? il : T;
    float4 eA = slp[1];
    float4 eB = slp[2];
    for (int t = 1; t < t_end; ++t) {
        float4 ec = eA; eA = eB;
        eB = slp[t + 2];

        float em0 = sel3(e0i, ec.x, ec.y, ec.z);
        float em1 = sel3(e1i, ec.x, ec.y, ec.z);
        float em2 = sel3(e2i, ec.x, ec.y, ec.z);

        float am1 = dpp_shr1_neg(a2);   // alpha[3*lane - 1]
        float am2 = dpp_shr1_neg(a1);   // alpha[3*lane - 2]

        float n0 = vv0 ? (lae3(a0, am1, sk0 ? am2 : NEGV) + em0) : NEGV;
        float n1 = vv1 ? (lae3(a1, a0,  sk1 ? am1 : NEGV) + em1) : NEGV;
        float n2 = vv2 ? (lae3(a2, a1,  sk2 ? a0  : NEGV) + em2) : NEGV;
        a0 = n0; a1 = n1; a2 = n2;
    }

    // ---- epilogue ----
    __shared__ float sa[192];
    {
        int l = 3 * lane;
        sa[l] = a0; sa[l + 1] = a1; sa[l + 2] = a2;
    }
    __syncthreads();
    if (lane == 0) {
        float last = sa[2 * tl];
        float prv  = (tl > 0) ? sa[2 * tl - 1] : NEGV;
        float m  = fmaxf(last, prv);
        float ll = m + __logf(__expf(last - m) + __expf(prv - m));
        float loss = (ll > -1e29f) ? -ll : 0.0f;
        float denom = (tl > 0) ? (float)tl : 1.0f;
        loss_out[p] = loss / denom;
    }
}

// Deterministic single-block reduction: out[0] = sum(v) / B
__global__ __launch_bounds__(256) void reduce_kernel(
    const float* __restrict__ v, float* __restrict__ out, int n, float invB)
{
    __shared__ float buf[256];
    float s = 0.f;
    for (int i = (int)threadIdx.x; i < n; i += 256) s += v[i];
    buf[threadIdx.x] = s;
    __syncthreads();
    for (int off = 128; off > 0; off >>= 1) {
        if ((int)threadIdx.x < off) buf[threadIdx.x] += buf[threadIdx.x + off];
        __syncthreads();
    }
    if (threadIdx.x == 0) out[0] = buf[0] * invB;
}

extern "C" void kernel_launch(void* const* d_in, const int* in_sizes, int n_in,
                              void* d_out, int out_size, void* d_ws, size_t ws_size,
                              hipStream_t stream) {
    const float* logits         = (const float*)d_in[0];
    const int*   targets        = (const int*)d_in[1];
    const int*   input_lengths  = (const int*)d_in[2];
    const int*   target_lengths = (const int*)d_in[3];
    float* out = (float*)d_out;

    const int B  = in_sizes[2];            // 32
    const int BF = in_sizes[3];            // B*F = 1120
    const int Ff = BF / B;                 // 35
    const int S  = in_sizes[1] / BF;       // 80
    const int C  = 2 * Ff + 1;             // 71
    const int T  = in_sizes[0] / (B * C);  // 600

    float* losses = (float*)d_ws;          // BF floats of scratch

    ctc_kernel<<<BF, 64, 0, stream>>>(logits, targets, input_lengths,
                                      target_lengths, losses, T, B, Ff, S);
    reduce_kernel<<<1, 256, 0, stream>>>(losses, out, BF, 1.0f / (float)B);
}

// Round 4
// 70.788 us; speedup vs baseline: 5.8054x; 3.4169x over previous
//
#include <hip/hip_runtime.h>

#define LN2 0.6931471805599453f

// lane i <- lane i-1 (value), lane 0 <- 0.0f
__device__ __forceinline__ float dpp_shr1_zero(float x) {
    return __int_as_float(__builtin_amdgcn_update_dpp(
        0, __float_as_int(x), 0x138, 0xF, 0xF, true));
}
// lane i <- lane i-1 (int), lane 0 keeps its own value
__device__ __forceinline__ int dpp_shr1_keep(int x) {
    return __builtin_amdgcn_update_dpp(x, x, 0x138, 0xF, 0xF, false);
}
// exact 2^clamp(d, -126, 127)
__device__ __forceinline__ float exp2i_clamped(int d) {
    int k = 127 + d;
    k = (k < 1) ? 1 : ((k > 254) ? 254 : k);
    return __uint_as_float(((unsigned)k) << 23);
}
__device__ __forceinline__ float sel3(int e, float v0, float v1, float v2) {
    return (e == 2) ? v2 : ((e == 1) ? v1 : v0);
}

struct CtcState {
    float a0, a1, a2;   // lane's 3 lattice states (linear, scaled by 2^-esum)
    float s1;           // 2^(esum_left - esum), refreshed each rescale
    int   esum;         // true alpha = a * 2^esum
};

__device__ __forceinline__ void ctc_step(const float4 ec, CtcState& st,
                                         float skm0, float skm1, float skm2,
                                         int e0i, int e1i, int e2i) {
    float em0 = sel3(e0i, ec.x, ec.y, ec.z);
    float em1 = sel3(e1i, ec.x, ec.y, ec.z);
    float em2 = sel3(e2i, ec.x, ec.y, ec.z);
    float am1 = dpp_shr1_zero(st.a2) * st.s1;   // alpha[l0-1] in local scale
    float am2 = dpp_shr1_zero(st.a1) * st.s1;   // alpha[l0-2] in local scale
    float n0 = fmaf(skm0, am2, st.a0 + am1) * em0;
    float n1 = fmaf(skm1, am1, st.a1 + st.a0) * em1;
    float n2 = fmaf(skm2, st.a0, st.a2 + st.a1) * em2;
    st.a0 = n0; st.a1 = n1; st.a2 = n2;
}

// Every 4 steps: per-lane power-of-2 renormalize + dead-lane exponent adoption
// + gap clamp (<= 2^64) + neighbor scale refresh. All exact (exponent-only).
__device__ __forceinline__ void ctc_rescale(CtcState& st) {
    float m = fmaxf(fmaxf(st.a0, st.a1), st.a2);        // >= 0
    int ebits = (int)(__float_as_uint(m) >> 23);
    bool dead = (ebits == 0);                           // zero/subnormal lane
    int de = dead ? 0 : (127 - ebits);
    float scz = dead ? 0.0f : exp2i_clamped(de);        // dead lanes: zero out
    st.a0 *= scz; st.a1 *= scz; st.a2 *= scz;
    st.esum -= de;
    // dead lanes adopt left neighbor's exponent (3-deep chain per window)
    #pragma unroll
    for (int r = 0; r < 3; ++r) {
        int en = dpp_shr1_keep(st.esum);
        st.esum = dead ? en : st.esum;
    }
    // clamp exponent gap to <= 64 (renormalize values if left is far above)
    int enf = dpp_shr1_keep(st.esum);
    int gap = enf - st.esum;
    int adj = (gap > 64) ? (gap - 64) : 0;
    float sc3 = exp2i_clamped(-adj);                    // ->0 if adj>126 (ok)
    st.a0 *= sc3; st.a1 *= sc3; st.a2 *= sc3;
    st.esum += adj;
    st.s1 = exp2i_clamped(gap - adj);                   // in [2^-126, 2^64]
}

// One wave per (b,f). Lane owns 3 adjacent lattice states, linear domain,
// per-lane block-floating-point. Emissions (linear softmax) staged in LDS.
__global__ __launch_bounds__(64) void ctc_kernel(
    const float* __restrict__ logits,        // [T, B, 2F+1]
    const int* __restrict__ targets,         // [B, F, S]
    const int* __restrict__ input_lengths,   // [B]
    const int* __restrict__ target_lengths,  // [B, F]
    float* __restrict__ loss_out,            // [B*F] (loss / tl)
    int T, int B, int Ff, int S)
{
    const int p = blockIdx.x;
    const int b = p / Ff;
    const int f = p - b * Ff;
    const int lane = (int)threadIdx.x;
    const int C = 2 * Ff + 1;
    const int L = 2 * S + 1;

    const int tl = target_lengths[p];
    const int il = input_lengths[b];
    const int tbase = p * S;

    // ---- per-lane static metadata: states l = 3*lane + j ----
    int e0i, e1i, e2i;
    float skm0, skm1, skm2;
    {
        int e[3]; float sk[3];
        const int l0 = 3 * lane;
        #pragma unroll
        for (int j = 0; j < 3; ++j) {
            int l = l0 + j;
            int ev = 2; float sok = 0.f;
            if (l < L && (l & 1)) {
                int s = (l - 1) >> 1;
                ev = targets[tbase + s];
                if (s >= 1) sok = (targets[tbase + s - 1] != ev) ? 1.f : 0.f;
            }
            e[j] = ev; sk[j] = sok;
        }
        e0i = e[0]; e1i = e[1]; e2i = e[2];
        skm0 = sk[0]; skm1 = sk[1]; skm2 = sk[2];
    }

    // ---- stage linear softmax into LDS: slp[t] = {p_pos, p_neg, p_blank, 0} ----
    __shared__ float4 slp[608];     // T + pad (zero) for deep prefetch
    {
        const float* lg = logits + (size_t)b * C;
        const size_t strideT = (size_t)B * C;
        for (int i = lane; i < 608; i += 64) {
            float4 v = make_float4(0.f, 0.f, 0.f, 0.f);
            if (i < T) {
                const float* r = lg + (size_t)i * strideT;
                float xp = r[f], xn = r[Ff + f], xb = r[2 * Ff];
                float m = fmaxf(fmaxf(xp, xn), xb);
                float ep = __expf(xp - m);
                float en = __expf(xn - m);
                float eb = __expf(xb - m);
                float inv = __builtin_amdgcn_rcpf(ep + en + eb);
                v = make_float4(ep * inv, en * inv, eb * inv, 0.f);
            }
            slp[i] = v;
        }
    }
    __syncthreads();

    // ---- t = 0 init ----
    CtcState st;
    {
        float4 E0 = slp[0];
        st.a0 = (lane == 0) ? E0.z : 0.f;
        st.a1 = (lane == 0 && tl > 0) ? sel3(e1i, E0.x, E0.y, E0.z) : 0.f;
        st.a2 = 0.f;
        st.s1 = 1.f;
        st.esum = 0;
    }

    const int t_end = (il < T) ? il : T;

    // ---- main loop: unroll 8 (two quads), rescale every 4, 8-deep LDS pipeline ----
    float4 EA0 = slp[1], EA1 = slp[2], EA2 = slp[3], EA3 = slp[4];
    float4 EB0 = slp[5], EB1 = slp[6], EB2 = slp[7], EB3 = slp[8];
    int t = 1;
    for (; t + 7 < t_end; t += 8) {
        ctc_rescale(st);
        ctc_step(EA0, st, skm0, skm1, skm2, e0i, e1i, e2i);
        ctc_step(EA1, st, skm0, skm1, skm2, e0i, e1i, e2i);
        ctc_step(EA2, st, skm0, skm1, skm2, e0i, e1i, e2i);
        ctc_step(EA3, st, skm0, skm1, skm2, e0i, e1i, e2i);
        EA0 = slp[t + 8];  EA1 = slp[t + 9];  EA2 = slp[t + 10]; EA3 = slp[t + 11];
        ctc_rescale(st);
        ctc_step(EB0, st, skm0, skm1, skm2, e0i, e1i, e2i);
        ctc_step(EB1, st, skm0, skm1, skm2, e0i, e1i, e2i);
        ctc_step(EB2, st, skm0, skm1, skm2, e0i, e1i, e2i);
        ctc_step(EB3, st, skm0, skm1, skm2, e0i, e1i, e2i);
        EB0 = slp[t + 12]; EB1 = slp[t + 13]; EB2 = slp[t + 14]; EB3 = slp[t + 15];
    }
    // tail (<= 7 steps, growth bounded, no rescale needed)
    for (; t < t_end; ++t) {
        float4 ec = slp[t];
        ctc_step(ec, st, skm0, skm1, skm2, e0i, e1i, e2i);
    }

    // ---- epilogue: loss from alpha[2tl], alpha[2tl-1] with per-lane exponents ----
    __shared__ float sa[192];
    __shared__ int   se[64];
    {
        int l = 3 * lane;
        sa[l] = st.a0; sa[l + 1] = st.a1; sa[l + 2] = st.a2;
        se[lane] = st.esum;
    }
    __syncthreads();
    if (lane == 0) {
        int l1 = 2 * tl;
        int l2 = (tl > 0) ? (2 * tl - 1) : 0;
        float v1 = sa[l1];
        float v2 = (tl > 0) ? sa[l2] : 0.f;
        int e1 = se[l1 / 3];
        int e2 = (tl > 0) ? se[l2 / 3] : 0;
        int em_ = (e1 > e2) ? e1 : e2;
        float sum = ldexpf(v1, e1 - em_) + ldexpf(v2, e2 - em_);
        float ll = (__log2f(sum) + (float)em_) * LN2;
        float loss = (ll > -1e29f) ? -ll : 0.0f;
        float denom = (tl > 0) ? (float)tl : 1.0f;
        loss_out[p] = loss / denom;
    }
}

// Deterministic single-block reduction: out[0] = sum(v) / B
__global__ __launch_bounds__(256) void reduce_kernel(
    const float* __restrict__ v, float* __restrict__ out, int n, float invB)
{
    __shared__ float buf[256];
    float s = 0.f;
    for (int i = (int)threadIdx.x; i < n; i += 256) s += v[i];
    buf[threadIdx.x] = s;
    __syncthreads();
    for (int off = 128; off > 0; off >>= 1) {
        if ((int)threadIdx.x < off) buf[threadIdx.x] += buf[threadIdx.x + off];
        __syncthreads();
    }
    if (threadIdx.x == 0) out[0] = buf[0] * invB;
}

extern "C" void kernel_launch(void* const* d_in, const int* in_sizes, int n_in,
                              void* d_out, int out_size, void* d_ws, size_t ws_size,
                              hipStream_t stream) {
    const float* logits         = (const float*)d_in[0];
    const int*   targets        = (const int*)d_in[1];
    const int*   input_lengths  = (const int*)d_in[2];
    const int*   target_lengths = (const int*)d_in[3];
    float* out = (float*)d_out;

    const int B  = in_sizes[2];            // 32
    const int BF = in_sizes[3];            // B*F = 1120
    const int Ff = BF / B;                 // 35
    const int S  = in_sizes[1] / BF;       // 80
    const int C  = 2 * Ff + 1;             // 71
    const int T  = in_sizes[0] / (B * C);  // 600

    float* losses = (float*)d_ws;          // BF floats of scratch

    ctc_kernel<<<BF, 64, 0, stream>>>(logits, targets, input_lengths,
                                      target_lengths, losses, T, B, Ff, S);
    reduce_kernel<<<1, 256, 0, stream>>>(losses, out, BF, 1.0f / (float)B);
}

// Round 5
// 55.870 us; speedup vs baseline: 7.3555x; 1.2670x over previous
//
#include <hip/hip_runtime.h>

#define LN2 0.6931471805599453f

// lane i <- lane i-1 (value), lane 0 <- 0.0f
__device__ __forceinline__ float dpp_shr1_zero(float x) {
    return __int_as_float(__builtin_amdgcn_update_dpp(
        0, __float_as_int(x), 0x138, 0xF, 0xF, true));
}
// lane i <- lane i-1 (int), lane 0 keeps its own value
__device__ __forceinline__ int dpp_shr1_keep(int x) {
    return __builtin_amdgcn_update_dpp(x, x, 0x138, 0xF, 0xF, false);
}
// exact 2^clamp(d, -126, 127)
__device__ __forceinline__ float exp2i_clamped(int d) {
    int k = 127 + d;
    k = (k < 1) ? 1 : ((k > 254) ? 254 : k);
    return __uint_as_float(((unsigned)k) << 23);
}
__device__ __forceinline__ float sel3(int e, float v0, float v1, float v2) {
    return (e == 2) ? v2 : ((e == 1) ? v1 : v0);
}

struct CtcState {
    float a0, a1, a2;   // lane's 3 lattice states (linear, scaled by 2^-esum)
    float s1;           // 2^(esum_left - esum), refreshed each rescale
    int   esum;         // true alpha = a * 2^esum
};

__device__ __forceinline__ void ctc_step(float em0, float em1, float em2,
                                         CtcState& st,
                                         float skm0, float skm1, float skm2) {
    float am1 = dpp_shr1_zero(st.a2) * st.s1;   // alpha[l0-1] in local scale
    float am2 = dpp_shr1_zero(st.a1) * st.s1;   // alpha[l0-2] in local scale
    float n0 = fmaf(skm0, am2, st.a0 + am1) * em0;
    float n1 = fmaf(skm1, am1, st.a1 + st.a0) * em1;
    float n2 = fmaf(skm2, st.a0, st.a2 + st.a1) * em2;
    st.a0 = n0; st.a1 = n1; st.a2 = n2;
}

// Every 8 steps: per-lane power-of-2 renormalize + dead-lane exponent adoption
// + gap clamp (<= 2^64) + neighbor scale refresh. All exact (exponent-only).
// Live lanes start each window in [1,2) and can decay at most ~2^-104/window,
// so only exact-zero (frontier-untouched) lanes ever read as dead.
__device__ __forceinline__ void ctc_rescale(CtcState& st) {
    float m = fmaxf(fmaxf(st.a0, st.a1), st.a2);        // >= 0
    int ebits = (int)(__float_as_uint(m) >> 23);
    bool dead = (ebits == 0);                           // zero/subnormal lane
    int de = dead ? 0 : (127 - ebits);
    float scz = dead ? 0.0f : exp2i_clamped(de);        // dead lanes: zero out
    st.a0 *= scz; st.a1 *= scz; st.a2 *= scz;
    st.esum -= de;
    // dead lanes adopt left neighbor's exponent (3-deep chain per window)
    #pragma unroll
    for (int r = 0; r < 3; ++r) {
        int en = dpp_shr1_keep(st.esum);
        st.esum = dead ? en : st.esum;
    }
    // clamp exponent gap to <= 64 (renormalize values if left is far above)
    int enf = dpp_shr1_keep(st.esum);
    int gap = enf - st.esum;
    int adj = (gap > 64) ? (gap - 64) : 0;
    float sc3 = exp2i_clamped(-adj);                    // ->0 if adj>126 (ok)
    st.a0 *= sc3; st.a1 *= sc3; st.a2 *= sc3;
    st.esum += adj;
    st.s1 = exp2i_clamped(gap - adj);                   // in [2^-126, 2^64]
}

// One wave per (b,f). Lane owns 3 adjacent lattice states, linear domain,
// per-lane block-floating-point. Emissions staged in LDS; per-step emission
// triplet fetched by 3 per-lane ds_read_b32 (broadcast groups, conflict-free),
// prefetched 4-8 steps ahead in rotating register banks.
__global__ __launch_bounds__(64) void ctc_kernel(
    const float* __restrict__ logits,        // [T, B, 2F+1]
    const int* __restrict__ targets,         // [B, F, S]
    const int* __restrict__ input_lengths,   // [B]
    const int* __restrict__ target_lengths,  // [B, F]
    float* __restrict__ loss_out,            // [B*F] (loss / tl)
    int T, int B, int Ff, int S)
{
    const int p = blockIdx.x;
    const int b = p / Ff;
    const int f = p - b * Ff;
    const int lane = (int)threadIdx.x;
    const int C = 2 * Ff + 1;
    const int L = 2 * S + 1;

    const int tl = target_lengths[p];
    const int il = input_lengths[b];
    const int tbase = p * S;

    // ---- per-lane static metadata: states l = 3*lane + j ----
    int e0i, e1i, e2i;
    float skm0, skm1, skm2;
    {
        int e[3]; float sk[3];
        const int l0 = 3 * lane;
        #pragma unroll
        for (int j = 0; j < 3; ++j) {
            int l = l0 + j;
            int ev = 2; float sok = 0.f;
            if (l < L && (l & 1)) {
                int s = (l - 1) >> 1;
                ev = targets[tbase + s];
                if (s >= 1) sok = (targets[tbase + s - 1] != ev) ? 1.f : 0.f;
            }
            e[j] = ev; sk[j] = sok;
        }
        e0i = e[0]; e1i = e[1]; e2i = e[2];
        skm0 = sk[0]; skm1 = sk[1]; skm2 = sk[2];
    }

    // ---- stage linear softmax into LDS: slp[t] = {p_pos, p_neg, p_blank, 0} ----
    __shared__ float4 slp[608];     // T + pad (zero) for deep prefetch
    {
        const float* lg = logits + (size_t)b * C;
        const size_t strideT = (size_t)B * C;
        for (int i = lane; i < 608; i += 64) {
            float4 v = make_float4(0.f, 0.f, 0.f, 0.f);
            if (i < T) {
                const float* r = lg + (size_t)i * strideT;
                float xp = r[f], xn = r[Ff + f], xb = r[2 * Ff];
                float m = fmaxf(fmaxf(xp, xn), xb);
                float ep = __expf(xp - m);
                float en = __expf(xn - m);
                float eb = __expf(xb - m);
                float inv = __builtin_amdgcn_rcpf(ep + en + eb);
                v = make_float4(ep * inv, en * inv, eb * inv, 0.f);
            }
            slp[i] = v;
        }
    }
    __syncthreads();

    // per-lane emission base pointers (byte offset e*4 within each 16B row)
    const char* base8 = (const char*)slp;
    const char* pt0 = base8 + (e0i << 2);
    const char* pt1 = base8 + (e1i << 2);
    const char* pt2 = base8 + (e2i << 2);
#define LDE(off, E) { E[0] = *(const float*)(pt0 + (off)); \
                      E[1] = *(const float*)(pt1 + (off)); \
                      E[2] = *(const float*)(pt2 + (off)); }

    // ---- t = 0 init ----
    CtcState st;
    {
        float4 E0 = slp[0];
        st.a0 = (lane == 0) ? E0.z : 0.f;
        st.a1 = (lane == 0 && tl > 0) ? sel3(e1i, E0.x, E0.y, E0.z) : 0.f;
        st.a2 = 0.f;
        st.s1 = 1.f;
        st.esum = 0;
    }

    const int t_end = (il < T) ? il : T;

    // ---- main loop: unroll 8, rescale every 8, rotating em banks (4+4) ----
    float A0[3], A1[3], A2[3], A3[3], B0[3], B1[3], B2[3], B3[3];
    int off = 16;                   // byte offset of row t=1
    LDE(off +   0, A0); LDE(off +  16, A1); LDE(off +  32, A2); LDE(off +  48, A3);
    LDE(off +  64, B0); LDE(off +  80, B1); LDE(off +  96, B2); LDE(off + 112, B3);
    int t = 1;
    for (; t + 7 < t_end; t += 8) {
        ctc_rescale(st);
        ctc_step(A0[0], A0[1], A0[2], st, skm0, skm1, skm2);
        ctc_step(A1[0], A1[1], A1[2], st, skm0, skm1, skm2);
        ctc_step(A2[0], A2[1], A2[2], st, skm0, skm1, skm2);
        ctc_step(A3[0], A3[1], A3[2], st, skm0, skm1, skm2);
        LDE(off + 128, A0); LDE(off + 144, A1); LDE(off + 160, A2); LDE(off + 176, A3);
        ctc_step(B0[0], B0[1], B0[2], st, skm0, skm1, skm2);
        ctc_step(B1[0], B1[1], B1[2], st, skm0, skm1, skm2);
        ctc_step(B2[0], B2[1], B2[2], st, skm0, skm1, skm2);
        ctc_step(B3[0], B3[1], B3[2], st, skm0, skm1, skm2);
        LDE(off + 192, B0); LDE(off + 208, B1); LDE(off + 224, B2); LDE(off + 240, B3);
        off += 128;
    }
    // tail (<= 7 steps, growth bounded, no rescale needed)
    for (; t < t_end; ++t) {
        int o = t << 4;
        float e0 = *(const float*)(pt0 + o);
        float e1 = *(const float*)(pt1 + o);
        float e2 = *(const float*)(pt2 + o);
        ctc_step(e0, e1, e2, st, skm0, skm1, skm2);
    }
#undef LDE

    // ---- epilogue: loss from alpha[2tl], alpha[2tl-1] with per-lane exponents ----
    __shared__ float sa[192];
    __shared__ int   se[64];
    {
        int l = 3 * lane;
        sa[l] = st.a0; sa[l + 1] = st.a1; sa[l + 2] = st.a2;
        se[lane] = st.esum;
    }
    __syncthreads();
    if (lane == 0) {
        int l1 = 2 * tl;
        int l2 = (tl > 0) ? (2 * tl - 1) : 0;
        float v1 = sa[l1];
        float v2 = (tl > 0) ? sa[l2] : 0.f;
        int e1 = se[l1 / 3];
        int e2 = (tl > 0) ? se[l2 / 3] : 0;
        int em_ = (e1 > e2) ? e1 : e2;
        float sum = ldexpf(v1, e1 - em_) + ldexpf(v2, e2 - em_);
        float ll = (__log2f(sum) + (float)em_) * LN2;
        float loss = (ll > -1e29f) ? -ll : 0.0f;
        float denom = (tl > 0) ? (float)tl : 1.0f;
        loss_out[p] = loss / denom;
    }
}

// Deterministic single-block reduction: out[0] = sum(v) / B
__global__ __launch_bounds__(256) void reduce_kernel(
    const float* __restrict__ v, float* __restrict__ out, int n, float invB)
{
    __shared__ float buf[256];
    float s = 0.f;
    for (int i = (int)threadIdx.x; i < n; i += 256) s += v[i];
    buf[threadIdx.x] = s;
    __syncthreads();
    for (int off = 128; off > 0; off >>= 1) {
        if ((int)threadIdx.x < off) buf[threadIdx.x] += buf[threadIdx.x + off];
        __syncthreads();
    }
    if (threadIdx.x == 0) out[0] = buf[0] * invB;
}

extern "C" void kernel_launch(void* const* d_in, const int* in_sizes, int n_in,
                              void* d_out, int out_size, void* d_ws, size_t ws_size,
                              hipStream_t stream) {
    const float* logits         = (const float*)d_in[0];
    const int*   targets        = (const int*)d_in[1];
    const int*   input_lengths  = (const int*)d_in[2];
    const int*   target_lengths = (const int*)d_in[3];
    float* out = (float*)d_out;

    const int B  = in_sizes[2];            // 32
    const int BF = in_sizes[3];            // B*F = 1120
    const int Ff = BF / B;                 // 35
    const int S  = in_sizes[1] / BF;       // 80
    const int C  = 2 * Ff + 1;             // 71
    const int T  = in_sizes[0] / (B * C);  // 600

    float* losses = (float*)d_ws;          // BF floats of scratch

    ctc_kernel<<<BF, 64, 0, stream>>>(logits, targets, input_lengths,
                                      target_lengths, losses, T, B, Ff, S);
    reduce_kernel<<<1, 256, 0, stream>>>(losses, out, BF, 1.0f / (float)B);
}

// Round 6
// 54.608 us; speedup vs baseline: 7.5254x; 1.0231x over previous
//
#include <hip/hip_runtime.h>

#define LN2 0.6931471805599453f

// lane i <- lane i-1 (value), lane 0 <- 0.0f
__device__ __forceinline__ float dpp_shr1_zero(float x) {
    return __int_as_float(__builtin_amdgcn_update_dpp(
        0, __float_as_int(x), 0x138, 0xF, 0xF, true));
}
// lane i <- lane i-1 (int), lane 0 keeps its own value
__device__ __forceinline__ int dpp_shr1_keep(int x) {
    return __builtin_amdgcn_update_dpp(x, x, 0x138, 0xF, 0xF, false);
}
// exact 2^clamp(d, -126, 127)
__device__ __forceinline__ float exp2i_clamped(int d) {
    int k = 127 + d;
    k = (k < 1) ? 1 : ((k > 254) ? 254 : k);
    return __uint_as_float(((unsigned)k) << 23);
}
__device__ __forceinline__ float sel3(int e, float v0, float v1, float v2) {
    return (e == 2) ? v2 : ((e == 1) ? v1 : v0);
}

struct CtcState {
    float a0, a1, a2;   // lane's 3 lattice states (linear, scaled by 2^-esum)
    float s1;           // 2^(esum_left - esum)
    float k0, k1;       // skm0*s1, skm1*s1 (exact: s1 is a power of 2)
    int   esum;         // true alpha = a * 2^esum
};

// 11 VALU (2 dpp + 9) per step.
__device__ __forceinline__ void ctc_step(float em0, float em1, float em2,
                                         CtcState& st, float skm2) {
    float d2 = dpp_shr1_zero(st.a2);    // alpha[l0-1] (left-neighbor scale)
    float d1 = dpp_shr1_zero(st.a1);    // alpha[l0-2]
    float n0 = fmaf(st.k0, d1, fmaf(st.s1, d2, st.a0)) * em0;
    float n1 = fmaf(st.k1, d2, st.a1 + st.a0) * em1;
    float n2 = fmaf(skm2, st.a0, st.a2 + st.a1) * em2;
    st.a0 = n0; st.a1 = n1; st.a2 = n2;
}

// Every 8 steps: per-lane power-of-2 renormalize + dead-lane exponent adoption
// (5-deep: frontier moves <= 16 states = 5.3 lanes per window) + gap clamp
// (<= 2^64) + neighbor scale refresh. All exact (exponent-only).
__device__ __forceinline__ void ctc_rescale(CtcState& st, float skm0, float skm1) {
    float m = fmaxf(fmaxf(st.a0, st.a1), st.a2);        // >= 0
    int ebits = (int)(__float_as_uint(m) >> 23);
    bool dead = (ebits == 0);                           // zero/subnormal lane
    int de = dead ? 0 : (127 - ebits);
    float scz = dead ? 0.0f : exp2i_clamped(de);        // dead lanes: zero out
    st.a0 *= scz; st.a1 *= scz; st.a2 *= scz;
    st.esum -= de;
    // dead lanes adopt left neighbor's exponent (5-deep chain per window)
    #pragma unroll
    for (int r = 0; r < 5; ++r) {
        int en = dpp_shr1_keep(st.esum);
        st.esum = dead ? en : st.esum;
    }
    // clamp exponent gap to <= 64 (renormalize values if left is far above)
    int enf = dpp_shr1_keep(st.esum);
    int gap = enf - st.esum;
    int adj = (gap > 64) ? (gap - 64) : 0;
    float sc3 = exp2i_clamped(-adj);                    // ->0 if adj>126 (ok)
    st.a0 *= sc3; st.a1 *= sc3; st.a2 *= sc3;
    st.esum += adj;
    st.s1 = exp2i_clamped(gap - adj);                   // in [2^-126, 2^64]
    st.k0 = skm0 * st.s1;
    st.k1 = skm1 * st.s1;
}

// One wave per (b,f). Lane owns 3 adjacent lattice states, linear domain,
// per-lane block-floating-point. Emissions staged in LDS; per-step triplet via
// 3 ds_read_b32 (broadcast groups, conflict-free), prefetched 16 steps ahead
// in 4 rotating register banks.
__global__ __launch_bounds__(64, 1) void ctc_kernel(
    const float* __restrict__ logits,        // [T, B, 2F+1]
    const int* __restrict__ targets,         // [B, F, S]
    const int* __restrict__ input_lengths,   // [B]
    const int* __restrict__ target_lengths,  // [B, F]
    float* __restrict__ loss_out,            // [B*F] (loss / tl)
    int T, int B, int Ff, int S)
{
    const int p = blockIdx.x;
    const int b = p / Ff;
    const int f = p - b * Ff;
    const int lane = (int)threadIdx.x;
    const int C = 2 * Ff + 1;
    const int L = 2 * S + 1;

    const int tl = target_lengths[p];
    const int il = input_lengths[b];
    const int tbase = p * S;

    // ---- per-lane static metadata: states l = 3*lane + j ----
    int e0i, e1i, e2i;
    float skm0, skm1, skm2;
    {
        int e[3]; float sk[3];
        const int l0 = 3 * lane;
        #pragma unroll
        for (int j = 0; j < 3; ++j) {
            int l = l0 + j;
            int ev = 2; float sok = 0.f;
            if (l < L && (l & 1)) {
                int s = (l - 1) >> 1;
                ev = targets[tbase + s];
                if (s >= 1) sok = (targets[tbase + s - 1] != ev) ? 1.f : 0.f;
            }
            e[j] = ev; sk[j] = sok;
        }
        e0i = e[0]; e1i = e[1]; e2i = e[2];
        skm0 = sk[0]; skm1 = sk[1]; skm2 = sk[2];
    }

    // ---- stage linear softmax into LDS (software-pipelined): slp[t] = {p_pos,p_neg,p_blank,0} ----
    __shared__ float4 slp[608];     // T + pad (zero) for deep prefetch
    {
        const float* lg = logits + (size_t)b * C;
        const size_t strideT = (size_t)B * C;
        float c0 = 0.f, c1 = 0.f, c2 = 0.f;
        if (lane < T) {
            const float* r = lg + (size_t)lane * strideT;
            c0 = r[f]; c1 = r[Ff + f]; c2 = r[2 * Ff];
        }
        #pragma unroll 1
        for (int j = 0; j < 10; ++j) {          // 10*64 = 640 >= 608
            int i = lane + (j << 6);
            int inx = i + 64;
            float n0 = 0.f, n1 = 0.f, n2 = 0.f;
            if (inx < T) {                       // issue next row's loads early
                const float* r = lg + (size_t)inx * strideT;
                n0 = r[f]; n1 = r[Ff + f]; n2 = r[2 * Ff];
            }
            float4 v = make_float4(0.f, 0.f, 0.f, 0.f);
            if (i < T) {
                float m = fmaxf(fmaxf(c0, c1), c2);
                float ep = __expf(c0 - m);
                float en = __expf(c1 - m);
                float eb = __expf(c2 - m);
                float inv = __builtin_amdgcn_rcpf(ep + en + eb);
                v = make_float4(ep * inv, en * inv, eb * inv, 0.f);
            }
            if (i < 608) slp[i] = v;
            c0 = n0; c1 = n1; c2 = n2;
        }
    }
    __syncthreads();

    // per-lane emission base pointers (byte offset e*4 within each 16B row)
    const char* base8 = (const char*)slp;
    const char* qt0 = base8 + (e0i << 2);
    const char* qt1 = base8 + (e1i << 2);
    const char* qt2 = base8 + (e2i << 2);

    // ---- t = 0 init ----
    CtcState st;
    {
        float4 E0 = slp[0];
        st.a0 = (lane == 0) ? E0.z : 0.f;
        st.a1 = (lane == 0 && tl > 0) ? sel3(e1i, E0.x, E0.y, E0.z) : 0.f;
        st.a2 = 0.f;
        st.s1 = 1.f; st.k0 = skm0; st.k1 = skm1;
        st.esum = 0;
    }

    const int t_end = (il < T) ? il : T;

    // ---- main loop: unroll 16, rescale every 8, 4 rotating banks 16 ahead ----
    const char* pr0 = qt0 + 16;     // row t=1
    const char* pr1 = qt1 + 16;
    const char* pr2 = qt2 + 16;
#define LDE(OFF, E) { E[0] = *(const float*)(pr0 + (OFF)); \
                      E[1] = *(const float*)(pr1 + (OFF)); \
                      E[2] = *(const float*)(pr2 + (OFF)); }
    float A0[3], A1[3], A2[3], A3[3], B0[3], B1[3], B2[3], B3[3];
    float C0[3], C1[3], C2[3], C3[3], D0[3], D1[3], D2[3], D3[3];
    LDE(  0, A0); LDE( 16, A1); LDE( 32, A2); LDE( 48, A3);
    LDE( 64, B0); LDE( 80, B1); LDE( 96, B2); LDE(112, B3);
    LDE(128, C0); LDE(144, C1); LDE(160, C2); LDE(176, C3);
    LDE(192, D0); LDE(208, D1); LDE(224, D2); LDE(240, D3);
    int t = 1;
    for (; t + 15 < t_end; t += 16) {
        ctc_rescale(st, skm0, skm1);
        ctc_step(A0[0], A0[1], A0[2], st, skm2);
        ctc_step(A1[0], A1[1], A1[2], st, skm2);
        ctc_step(A2[0], A2[1], A2[2], st, skm2);
        ctc_step(A3[0], A3[1], A3[2], st, skm2);
        LDE(256, A0); LDE(272, A1); LDE(288, A2); LDE(304, A3);
        ctc_step(B0[0], B0[1], B0[2], st, skm2);
        ctc_step(B1[0], B1[1], B1[2], st, skm2);
        ctc_step(B2[0], B2[1], B2[2], st, skm2);
        ctc_step(B3[0], B3[1], B3[2], st, skm2);
        LDE(320, B0); LDE(336, B1); LDE(352, B2); LDE(368, B3);
        ctc_rescale(st, skm0, skm1);
        ctc_step(C0[0], C0[1], C0[2], st, skm2);
        ctc_step(C1[0], C1[1], C1[2], st, skm2);
        ctc_step(C2[0], C2[1], C2[2], st, skm2);
        ctc_step(C3[0], C3[1], C3[2], st, skm2);
        LDE(384, C0); LDE(400, C1); LDE(416, C2); LDE(432, C3);
        ctc_step(D0[0], D0[1], D0[2], st, skm2);
        ctc_step(D1[0], D1[1], D1[2], st, skm2);
        ctc_step(D2[0], D2[1], D2[2], st, skm2);
        ctc_step(D3[0], D3[1], D3[2], st, skm2);
        LDE(448, D0); LDE(464, D1); LDE(480, D2); LDE(496, D3);
        pr0 += 256; pr1 += 256; pr2 += 256;
    }
#undef LDE
    // tail (<= 15 steps, growth bounded by gap clamp, no rescale needed)
    for (; t < t_end; ++t) {
        int o = t << 4;
        float e0 = *(const float*)(qt0 + o);
        float e1 = *(const float*)(qt1 + o);
        float e2 = *(const float*)(qt2 + o);
        ctc_step(e0, e1, e2, st, skm2);
    }

    // ---- epilogue: loss from alpha[2tl], alpha[2tl-1] with per-lane exponents ----
    __shared__ float sa[192];
    __shared__ int   se[64];
    {
        int l = 3 * lane;
        sa[l] = st.a0; sa[l + 1] = st.a1; sa[l + 2] = st.a2;
        se[lane] = st.esum;
    }
    __syncthreads();
    if (lane == 0) {
        int l1 = 2 * tl;
        int l2 = (tl > 0) ? (2 * tl - 1) : 0;
        float v1 = sa[l1];
        float v2 = (tl > 0) ? sa[l2] : 0.f;
        int e1 = se[l1 / 3];
        int e2 = (tl > 0) ? se[l2 / 3] : 0;
        int em_ = (e1 > e2) ? e1 : e2;
        float sum = ldexpf(v1, e1 - em_) + ldexpf(v2, e2 - em_);
        float ll = (__log2f(sum) + (float)em_) * LN2;
        float loss = (ll > -1e29f) ? -ll : 0.0f;
        float denom = (tl > 0) ? (float)tl : 1.0f;
        loss_out[p] = loss / denom;
    }
}

// Deterministic single-block reduction: out[0] = sum(v) / B
__global__ __launch_bounds__(256) void reduce_kernel(
    const float* __restrict__ v, float* __restrict__ out, int n, float invB)
{
    __shared__ float buf[256];
    float s = 0.f;
    for (int i = (int)threadIdx.x; i < n; i += 256) s += v[i];
    buf[threadIdx.x] = s;
    __syncthreads();
    for (int off = 128; off > 0; off >>= 1) {
        if ((int)threadIdx.x < off) buf[threadIdx.x] += buf[threadIdx.x + off];
        __syncthreads();
    }
    if (threadIdx.x == 0) out[0] = buf[0] * invB;
}

extern "C" void kernel_launch(void* const* d_in, const int* in_sizes, int n_in,
                              void* d_out, int out_size, void* d_ws, size_t ws_size,
                              hipStream_t stream) {
    const float* logits         = (const float*)d_in[0];
    const int*   targets        = (const int*)d_in[1];
    const int*   input_lengths  = (const int*)d_in[2];
    const int*   target_lengths = (const int*)d_in[3];
    float* out = (float*)d_out;

    const int B  = in_sizes[2];            // 32
    const int BF = in_sizes[3];            // B*F = 1120
    const int Ff = BF / B;                 // 35
    const int S  = in_sizes[1] / BF;       // 80
    const int C  = 2 * Ff + 1;             // 71
    const int T  = in_sizes[0] / (B * C);  // 600

    float* losses = (float*)d_ws;          // BF floats of scratch

    ctc_kernel<<<BF, 64, 0, stream>>>(logits, targets, input_lengths,
                                      target_lengths, losses, T, B, Ff, S);
    reduce_kernel<<<1, 256, 0, stream>>>(losses, out, BF, 1.0f / (float)B);
}